// Round 4
// baseline (270.459 us; speedup 1.0000x reference)
//
#include <hip/hip_runtime.h>
#include <stdint.h>

// Keep every f32 op un-fused: the reference (numpy/jax f32) computes
// inter = ih*iw; union = a_i + a_j - inter as separate rounded ops. With
// HIP's default -ffp-contract=fast the subtract would fuse into an FMA and
// could flip borderline iou > 0.5 decisions -> wrong box selected.
#pragma clang fp contract(off)

namespace {
constexpr int kN = 21824;      // 128^2 + 64^2 + 32^2 + 16^2 + 8^2
constexpr int kB = 16;
constexpr int kC = 80;
constexpr int kK = 256;        // K_CAND
constexpr int kMaxPC = 100;
constexpr int kMaxDet = 100;
constexpr int kBins1 = 2048;   // level-0 histogram bins
constexpr int kCap = 1536;     // per-row global candidate capacity (u64 keys)
constexpr int kSortN = 512;    // qualifier cap == bitonic sort size
constexpr int kRows = kB * kC; // 1280
constexpr int kTiles = kN / 64;            // 341
constexpr int kTPB = 6;                    // tiles (of 64 anchors) per scan block
constexpr int kGScan = (kTiles + kTPB - 1) / kTPB;   // 57 blocks per batch
constexpr int kLCap = 48;      // per-class per-block LDS list capacity
// Prune floor for the fast path. For this benchmark's product-of-uniforms
// scores, #(s > 0.72) per row ~ mean 950, sd 30 -> inside [kK, kCap] with
// ~10-sigma margin; per-block per-class count ~ mean 17, sd 4 -> < kLCap
// with ~7.8-sigma margin. ANY violation routes to the exact fallback
// (overflow marks the row counter > kCap), so this is a speed heuristic
// only, never a correctness assumption.
constexpr float kThr = 0.72f;
}

// ---- 48-bit sort key: score bits (high 32) | (0xFFFF - index) (low 16) ----
// scores are >= 0 so the raw f32 bit pattern is order-monotone; the index
// complement reproduces jax top_k's stable tie-break (lower index wins).
__device__ __forceinline__ uint64_t make_key(float s, int n) {
  return ((uint64_t)__float_as_uint(s) << 16) | (uint32_t)(0xFFFF - n);
}

// Block-wide (256 threads) inclusive prefix scan.
__device__ uint32_t block_scan_incl(uint32_t val) {
  __shared__ uint32_t wsum[4];
  int lane = threadIdx.x & 63;
  int wave = threadIdx.x >> 6;
  for (int d = 1; d < 64; d <<= 1) {
    uint32_t t = __shfl_up(val, (unsigned)d, 64);
    if (lane >= d) val += t;
  }
  if (lane == 63) wsum[wave] = val;
  __syncthreads();
  uint32_t off = 0;
  for (int w = 0; w < wave; ++w) off += wsum[w];
  __syncthreads();
  return val + off;
}

// ---- key sources for the refinement select ----
// each(f): f(key) for valid keys only (may be lane-divergent; used for
//          histogram passes where atomics are address-spread).
// each2(f): f(key, valid) executed CONVERGENTLY by every lane of every wave
//          (fixed trip count) -> safe for __ballot aggregation in f.
// Fast path: <=6 list keys per thread, held in registers.
struct RegSrc {
  uint64_t k[6];
  int cnt;                      // valid entries in k[] (prefix)
  template <class F> __device__ void each(F f) const {
    #pragma unroll
    for (int j = 0; j < 6; ++j)
      if (j < cnt) f(k[j]);
  }
  template <class F> __device__ void each2(F f) const {
    #pragma unroll
    for (int j = 0; j < 6; ++j) f(k[j], j < cnt);   // k[j] garbage if !valid; q anded with valid
  }
};
// Exact fallback: recompute scores from the strided class column each pass.
struct ColSrc {
  const float* cl;              // clfs + b*kN*kC + c  (stride kC)
  const float* ct;              // ctrs + b*kN
  template <class F> __device__ void each(F f) const {
    for (int n = threadIdx.x; n < kN; n += 256)
      f(make_key(cl[(size_t)n * kC] * ct[n], n));
  }
  template <class F> __device__ void each2(F f) const {
    constexpr int kNr = (kN + 255) & ~255;
    for (int n = threadIdx.x; n < kNr; n += 256) {
      bool v = n < kN;
      float s = v ? cl[(size_t)n * kC] * ct[n] : 0.0f;
      f(make_key(s, n), v);
    }
  }
};
struct ArrSrc {
  const float* s;
  int count;
  template <class F> __device__ void each(F f) const {
    for (int i = threadIdx.x; i < count; i += 256) f(make_key(s[i], i));
  }
  template <class F> __device__ void each2(F f) const {
    int cr = (count + 255) & ~255;
    for (int i = threadIdx.x; i < cr; i += 256) {
      bool v = i < count;
      float sv = v ? s[i] : 0.0f;
      f(make_key(sv, i), v);
    }
  }
};

// ---- exact top-K floor via histogram refinement, then gather qualifiers.
// Generic (FAST=false): level-0 bins = top 11 key bits (k >> 37).
// FAST=true (nms fast path): every key's score is in (kThr, 1.0) -> float
// exponent is exactly 126 -> key bits [47:39] are the constant 0x7E. Binning
// on the next-lower mantissa bits, bin = (k >> 28) & 0x7FF, is then
// order-monotone (all higher bits equal) and spreads the ~950 keys over
// ~1100 bins (vs 3 hot bins for the generic binning). The refinement loop
// below still handles Sge > cap for either binning (prefix carries the
// constant top bits), so this is a speed specialization only.
// The final gather is wave-aggregated: __ballot + one atomic per wave per
// key slot, instead of ~950 serialized same-address atomicAdd returns.
// Returns Scnt (= #keys >= floor, K <= Scnt <= cap) with the qualifiers in
// cbuf[0..Scnt) (unordered -- the caller sorts).
template <class Src, bool FAST>
__device__ int refine_gather(const Src& src, int K, int cap,
                             uint32_t* hist, uint64_t* cbuf) {
  __shared__ int sel_bin;
  __shared__ uint32_t sel_hd, sel_above, qcnt;
  int tid = threadIdx.x;

  for (int i = tid; i < kBins1; i += 256) hist[i] = 0;
  __syncthreads();
  src.each([&](uint64_t k) {
    uint32_t bin = FAST ? (uint32_t)((k >> 28) & 0x7FF) : (uint32_t)(k >> 37);
    atomicAdd(&hist[bin], 1u);
  });
  __syncthreads();
  uint32_t krem = (uint32_t)K;
  {
    uint32_t bl[8], v = 0;
    int base = kBins1 - 1 - 8 * tid;      // descending scan, 8 bins/thread
    for (int j = 0; j < 8; ++j) { bl[j] = hist[base - j]; v += bl[j]; }
    uint32_t S = block_scan_incl(v);
    if (S >= krem && (S - v) < krem) {
      uint32_t cum = S - v;
      for (int j = 0; j < 8; ++j) {
        cum += bl[j];
        if (cum >= krem) { sel_bin = base - j; sel_hd = bl[j]; sel_above = cum - bl[j]; break; }
      }
    }
    __syncthreads();
  }
  // prefix = all key bits above `shift`; for FAST include the constant
  // exponent bits: (k>>28) = (0x7E << 11) | bin = 0x3F000 | bin.
  uint64_t prefix = FAST ? (uint64_t)(0x3F000u | (uint32_t)sel_bin)
                         : (uint64_t)sel_bin;
  int shift = FAST ? 28 : 37;
  krem = (uint32_t)K - sel_above;
  uint32_t Sge = ((uint32_t)K - krem) + sel_hd;
  __syncthreads();

  while (Sge > (uint32_t)cap) {
    int w = (shift > 8) ? 8 : shift;
    int ns = shift - w, bins = 1 << w, hs = shift;
    for (int i = tid; i < bins; i += 256) hist[i] = 0;
    __syncthreads();
    uint64_t pfx = prefix;
    src.each([&](uint64_t k) {
      if ((k >> hs) == pfx)
        atomicAdd(&hist[(uint32_t)(k >> ns) & (bins - 1)], 1u);
    });
    __syncthreads();
    uint32_t v = (tid < bins) ? hist[bins - 1 - tid] : 0;
    uint32_t S = block_scan_incl(v);
    if (v && S >= krem && (S - v) < krem) {
      sel_bin = bins - 1 - tid; sel_hd = v; sel_above = S - v;
    }
    __syncthreads();
    prefix = (prefix << w) | (uint32_t)sel_bin;
    krem -= sel_above;
    Sge = ((uint32_t)K - krem) + sel_hd;
    shift = ns;
    __syncthreads();
  }

  uint64_t L = prefix << shift;
  if (tid == 0) qcnt = 0;
  __syncthreads();
  {
    int lane = tid & 63;
    uint64_t lmask = (1ull << lane) - 1ull;
    src.each2([&](uint64_t k, bool valid) {
      bool q = valid && (k >= L);
      unsigned long long m = __ballot(q);
      uint32_t base = 0;
      if (lane == 0 && m) base = atomicAdd(&qcnt, (uint32_t)__popcll(m));
      base = __shfl(base, 0, 64);
      if (q) {
        uint32_t p = base + (uint32_t)__popcll(m & lmask);
        if (p < (uint32_t)cap) cbuf[p] = k;
      }
    });
  }
  __syncthreads();
  int Scnt = (int)qcnt;
  return Scnt > cap ? cap : Scnt;       // == Sge <= cap by construction
}

// ---- bitonic sort of 512 keys in LDS, descending, 2 elements/thread. ----
// Thread L owns elements 2L, 2L+1. For element-distance j <= 64 the partner
// lane is L ^ (j/2) -> wave-local __shfl_xor, no LDS, no barrier. Only
// j in {256,128} cross waves (3 phases) and go through LDS. Keys must be
// unique (index bits guarantee it); zero-padding sorts last. Ends with the
// sorted array redistributed to sortb[] (rank r at sortb[r]) + barrier.
__device__ __forceinline__ void bitonic512_desc(uint64_t* sortb) {
  int tid = threadIdx.x;
  uint64_t e0 = sortb[2 * tid], e1 = sortb[2 * tid + 1];
  #pragma unroll
  for (int k2 = 2; k2 <= kSortN; k2 <<= 1) {
    #pragma unroll
    for (int j = k2 >> 1; j >= 2; j >>= 1) {
      bool up = ((tid & (k2 >> 1)) == 0);      // element (2L)&k2 == 0
      uint64_t p0, p1;
      bool low;
      if (j >= 128) {                          // cross-wave via LDS
        __syncthreads();                       // prior reads done
        sortb[2 * tid] = e0; sortb[2 * tid + 1] = e1;
        __syncthreads();
        int pi = (2 * tid) ^ j;                // j even -> partner pair contiguous
        p0 = sortb[pi]; p1 = sortb[pi + 1];
        low = ((tid & (j >> 1)) == 0);
      } else {                                 // wave-local via shuffle
        int d = j >> 1;
        p0 = (uint64_t)__shfl_xor((unsigned long long)e0, d, 64);
        p1 = (uint64_t)__shfl_xor((unsigned long long)e1, d, 64);
        low = ((tid & d) == 0);
      }
      bool keepMax = (up == low);
      e0 = (keepMax == (e0 > p0)) ? e0 : p0;
      e1 = (keepMax == (e1 > p1)) ? e1 : p1;
    }
    { // j == 1: in-thread pair (2L, 2L+1)
      bool up = ((tid & (k2 >> 1)) == 0);
      bool sw = up ? (e0 < e1) : (e0 > e1);
      uint64_t t0 = sw ? e1 : e0, t1 = sw ? e0 : e1;
      e0 = t0; e1 = t1;
    }
  }
  __syncthreads();
  sortb[2 * tid] = e0; sortb[2 * tid + 1] = e1;
  __syncthreads();
}

// ---- fused score (clf*ctr) + prune, two-level append ----
__global__ __launch_bounds__(256) void score_scan_kernel(
    const float* __restrict__ clfs, const float* __restrict__ ctrs,
    uint32_t* __restrict__ gcnt, uint64_t* __restrict__ glist) {
  int b = blockIdx.y;
  int t0 = blockIdx.x * kTPB;
  int t1 = t0 + kTPB; if (t1 > kTiles) t1 = kTiles;
  int nbase = t0 * 64;
  int nanch = (t1 - t0) * 64;

  __shared__ uint64_t lbuf[kC][kLCap + 1]; // +1 pad: append banks spread
  __shared__ uint32_t lcnt[kC];
  __shared__ uint32_t gbase[kC];
  __shared__ float ct[kTPB * 64];
  int tid = threadIdx.x;
  for (int i = tid; i < kC; i += 256) lcnt[i] = 0;
  for (int i = tid; i < nanch; i += 256) ct[i] = ctrs[(size_t)b * kN + nbase + i];
  __syncthreads();

  const float4* src = (const float4*)(clfs + ((size_t)b * kN + nbase) * kC);
  int n4 = nanch * (kC / 4);             // 20 float4 per anchor
  // software prefetch: issue the next global load before the atomic-laden
  // append body (side effects otherwise pin the loads behind the branches).
  float4 v = (tid < n4) ? src[tid] : float4{0, 0, 0, 0};
  for (int e = tid; e < n4; e += 256) {
    int en = e + 256;
    float4 vn = (en < n4) ? src[en] : float4{0, 0, 0, 0};
    int a = e / 20;                      // anchor within chunk
    int c0 = (e % 20) * 4;               // class of component .x (4 | 80)
    float cv = ct[a];
    int n = nbase + a;
    float sv[4] = {v.x * cv, v.y * cv, v.z * cv, v.w * cv};
    #pragma unroll
    for (int j = 0; j < 4; ++j) {
      if (sv[j] > kThr) {
        int c = c0 + j;
        uint32_t p = atomicAdd(&lcnt[c], 1u);
        if (p < kLCap) lbuf[c][p] = make_key(sv[j], n);
      }
    }
    v = vn;
  }
  __syncthreads();

  // parallel reservations: 80 concurrent global atomics (lanes), then copy.
  if (tid < kC) {
    uint32_t m = lcnt[tid];
    int row = b * kC + tid;
    if (m > kLCap) {                     // overflow -> force exact fallback
      atomicAdd(&gcnt[row], (uint32_t)(kCap + 1));
      gbase[tid] = 0xFFFFFFFFu;
    } else {
      gbase[tid] = m ? atomicAdd(&gcnt[row], m) : 0u;
    }
  }
  __syncthreads();

  int lane = tid & 63, wave = tid >> 6;
  for (int c = wave * 20; c < wave * 20 + 20; ++c) {
    uint32_t m = lcnt[c];
    uint32_t base = gbase[c];
    if (base == 0xFFFFFFFFu || m == 0) continue;
    if (m > kLCap) m = kLCap;
    int row = b * kC + c;
    for (uint32_t i = lane; i < m; i += 64) {
      uint32_t p = base + i;
      if (p < kCap) glist[(size_t)row * kCap + p] = lbuf[c][i];
    }
  }
}

// ---- per-(batch,class): list -> exact top-256 -> bit-matrix NMS -> top-100 ----
__global__ __launch_bounds__(256) void nms_class_kernel(
    const uint32_t* __restrict__ gcnt, const uint64_t* __restrict__ glist,
    const float* __restrict__ clfs, const float* __restrict__ ctrs,
    const float* __restrict__ regs,
    float* __restrict__ cls_boxes, float* __restrict__ cls_scores) {
  int row = blockIdx.x;
  int b = row / kC, c = row % kC;
  int tid = threadIdx.x;
  int lane = tid & 63, wave = tid >> 6;

  __shared__ union alignas(16) {
    uint32_t hist[kBins1];               // select phase (8 KB)
    uint64_t sortb[kSortN];              // qualifier + sort buffer (4 KB)
    uint32_t supm[kK][8];                // NMS suppression bit-matrix (8 KB)
  } hu;
  __shared__ float4 boxf4[kK];           // y1,x1,y2,x2 (4 KB)
  __shared__ float barea[kK];
  __shared__ uint64_t kinit[4];          // initial keep mask (valid bits)
  __shared__ uint64_t kfin[4];           // final keep mask

  // fast path: pruned list holds a superset of the top-256
  // (cnt >= kK  ==> the 256th-largest score > kThr ==> all top-256 listed;
  //  cnt <= kCap ==> no block overflowed and no append was dropped)
  uint32_t cnt = gcnt[row];
  int Scnt;
  if (cnt >= (uint32_t)kK && cnt <= (uint32_t)kCap) {
    RegSrc rs; rs.cnt = 0;
    const uint64_t* gl = glist + (size_t)row * kCap;
    #pragma unroll
    for (int j = 0; j < 6; ++j) {
      int i = tid + j * 256;
      if (i < (int)cnt) { rs.k[j] = gl[i]; rs.cnt = j + 1; }
    }
    // gather straight into the sort buffer (hist region is dead by then);
    // FAST binning: all keys have score in (kThr,1) -> exp bits constant.
    Scnt = refine_gather<RegSrc, true>(rs, kK, kSortN, hu.hist, hu.sortb);
  } else {
    ColSrc cs{clfs + (size_t)b * kN * kC + c, ctrs + (size_t)b * kN};
    Scnt = refine_gather<ColSrc, false>(cs, kK, kSortN, hu.hist, hu.sortb);
  }

  // sort 512 (pad with zeros), rank tid == thread tid's candidate
  for (int i = Scnt + tid; i < kSortN; i += 256) hu.sortb[i] = 0;
  __syncthreads();
  bitonic512_desc(hu.sortb);
  uint64_t myk = hu.sortb[tid];
  __syncthreads();                       // all sortb reads before supm zero

  // decode my candidate's box directly from regs (fused decode)
  int n = 0xFFFF - (int)(myk & 0xFFFF);
  float sc_v = __uint_as_float((uint32_t)(myk >> 16));
  int off, hl;
  float sf;
  if (n < 16384)      { off = 0;     hl = 7; sf = 8.f;   }
  else if (n < 20480) { off = 16384; hl = 6; sf = 16.f;  }
  else if (n < 21504) { off = 20480; hl = 5; sf = 32.f;  }
  else if (n < 21760) { off = 21504; hl = 4; sf = 64.f;  }
  else                { off = 21760; hl = 3; sf = 128.f; }
  int kk = n - off;
  // meshgrid(h, w) with 'xy' indexing -> gy = k % H, gx = k / H
  float gx = (float)(kk >> hl);
  float gy = (float)(kk & ((1 << hl) - 1));
  const float4 r = ((const float4*)regs)[(size_t)b * kN + n];
  float4 mybox;
  mybox.x = (gy - r.z) * sf;             // y1
  mybox.y = (gx - r.x) * sf;             // x1
  mybox.z = (gy + r.w) * sf;             // y2
  mybox.w = (gx + r.y) * sf;             // x2
  float my_a = (mybox.z - mybox.x) * (mybox.w - mybox.y);
  boxf4[tid] = mybox;
  barea[tid] = my_a;
  unsigned long long vm = __ballot(sc_v > 0.05f);   // valid = top_s > CONF_THR
  if (lane == 0) kinit[wave] = vm;
  // zero the suppression matrix (sortb/hist no longer needed)
  {
    uint64_t* sp = (uint64_t*)&hu.supm[0][0];
    #pragma unroll
    for (int q = 0; q < 4; ++q) sp[tid + q * 256] = 0;
  }
  __syncthreads();

  // phase A: row-owner lockstep IoU. Thread t owns row t (its box is
  // already in registers); every lane of wave w iterates the SAME column
  // word (wave w needs cols > 64w, so words 2w..7). Uniform LDS addresses
  // -> hardware broadcast, zero bank conflicts; each row's suppression
  // words are written only by their owner -> plain ds_write, no atomics.
  // Columns j <= t are computed but masked off (word tw keeps bits > t&31;
  // words < tw are skipped and stay zeroed). Exact predicate:
  // RN(inter/unc) > 0.5  <=>  inter > (0.5+2^-25)*unc (tie rounds-to-even
  // down)  <=>  inter+inter > unc in pure f32 (no f32 value lies in
  // (unc/2, (0.5+2^-25)*unc] since ulp(u)/u > 2^-24 for normals; unc >=
  // 1e-8 is always normal). Bit-exact vs the reference.
  {
    int tw = tid >> 5;
    uint32_t meq = 0xFFFFFFFEu << (tid & 31);   // bits j > t within word tw
    for (int w = wave << 1; w < 8; ++w) {
      const float4* bp = boxf4 + (w << 5);
      const float* ap = barea + (w << 5);
      uint32_t cur = 0;
      #pragma unroll
      for (int s = 0; s < 32; ++s) {
        const float4 Bx = bp[s];
        float aB = ap[s];
        float yy1 = fmaxf(mybox.x, Bx.x);
        float yy2 = fminf(mybox.z, Bx.z);
        float xx1 = fmaxf(mybox.y, Bx.y);
        float xx2 = fminf(mybox.w, Bx.w);
        float ih = fmaxf(yy2 - yy1, 0.0f);
        float iw = fmaxf(xx2 - xx1, 0.0f);
        float inter = ih * iw;
        float un = (aB + my_a) - inter;
        float unc = fmaxf(un, 1e-8f);
        cur |= (inter + inter > unc) ? (1u << s) : 0u;
      }
      uint32_t mask = (w > tw) ? 0xFFFFFFFFu : ((w == tw) ? meq : 0u);
      if (mask) hu.supm[tid][w] = cur & mask;
    }
  }
  __syncthreads();

  // phase B: greedy resolution by wave 0 only. Rows are prefetched in
  // chunks of 4 (address-independent LDS loads overlap the serial VALU
  // apply chain); rows are 32B-aligned so each is two ds_read_b128, and
  // the uniform addresses broadcast conflict-free.
  if (wave == 0) {
    uint64_t kw0 = kinit[0], kw1 = kinit[1], kw2 = kinit[2], kw3 = kinit[3];
    #define NMS_SECTION(W, KW)                                              \
      _Pragma("unroll")                                                     \
      for (int ch = 0; ch < 16; ++ch) {                                     \
        const ulonglong2* s0 = (const ulonglong2*)hu.supm[(W << 6) + ch * 4 + 0]; \
        const ulonglong2* s1 = (const ulonglong2*)hu.supm[(W << 6) + ch * 4 + 1]; \
        const ulonglong2* s2 = (const ulonglong2*)hu.supm[(W << 6) + ch * 4 + 2]; \
        const ulonglong2* s3 = (const ulonglong2*)hu.supm[(W << 6) + ch * 4 + 3]; \
        ulonglong2 aL = s0[0], aH = s0[1];                                  \
        ulonglong2 bL = s1[0], bH = s1[1];                                  \
        ulonglong2 cL = s2[0], cH = s2[1];                                  \
        ulonglong2 dL = s3[0], dH = s3[1];                                  \
        if ((KW >> (ch * 4 + 0)) & 1ull) { kw0 &= ~aL.x; kw1 &= ~aL.y; kw2 &= ~aH.x; kw3 &= ~aH.y; } \
        if ((KW >> (ch * 4 + 1)) & 1ull) { kw0 &= ~bL.x; kw1 &= ~bL.y; kw2 &= ~bH.x; kw3 &= ~bH.y; } \
        if ((KW >> (ch * 4 + 2)) & 1ull) { kw0 &= ~cL.x; kw1 &= ~cL.y; kw2 &= ~cH.x; kw3 &= ~cH.y; } \
        if ((KW >> (ch * 4 + 3)) & 1ull) { kw0 &= ~dL.x; kw1 &= ~dL.y; kw2 &= ~dH.x; kw3 &= ~dH.y; } \
      }
    NMS_SECTION(0, kw0)
    NMS_SECTION(1, kw1)
    NMS_SECTION(2, kw2)
    NMS_SECTION(3, kw3)
    #undef NMS_SECTION
    if (lane == 0) { kfin[0] = kw0; kfin[1] = kw1; kfin[2] = kw2; kfin[3] = kw3; }
  }
  __syncthreads();

  uint64_t kw0 = kfin[0], kw1 = kfin[1], kw2 = kfin[2], kw3 = kfin[3];
  uint64_t ww = (wave == 0) ? kw0 : (wave == 1) ? kw1 : (wave == 2) ? kw2 : kw3;
  bool keptf = (ww >> lane) & 1ull;
  int kept_total = (int)(__popcll(kw0) + __popcll(kw1) +
                         __popcll(kw2) + __popcll(kw3));
  int kept_before = (int)__popcll(ww & ((1ull << lane) - 1ull));
  if (wave > 0) kept_before += (int)__popcll(kw0);
  if (wave > 1) kept_before += (int)__popcll(kw1);
  if (wave > 2) kept_before += (int)__popcll(kw2);

  // stable top-100 of kept scores: kept candidates are already in descending
  // (score,-index) order; zero slots tie-break by position. Final order =
  // kept (tid order) then suppressed (tid order) == reference stable top_k.
  int rank2 = keptf ? kept_before : (kept_total + tid - kept_before);
  if (rank2 < kMaxPC) {
    float ks = keptf ? sc_v : 0.0f;
    size_t obase = ((size_t)row) * kMaxPC + rank2;
    cls_scores[obase] = ks;
    float* ob = cls_boxes + obase * 4;
    ob[0] = mybox.x; ob[1] = mybox.y; ob[2] = mybox.z; ob[3] = mybox.w;
  }
}

// ---- per-batch: stable top-100 over 80*100 entries, write final outputs ----
__global__ __launch_bounds__(256) void final_topk_kernel(
    const float* __restrict__ cls_scores, const float* __restrict__ cls_boxes,
    float* __restrict__ out) {
  int b = blockIdx.x;
  int tid = threadIdx.x;
  const int M = kC * kMaxPC;  // 8000
  __shared__ union alignas(16) {
    uint32_t hist[kBins1];               // 8 KB
    uint64_t sortb[kSortN];              // 4 KB (hist dead at gather time)
  } hu;

  ArrSrc as{cls_scores + (size_t)b * M, M};
  int Scnt = refine_gather<ArrSrc, false>(as, kMaxDet, kSortN, hu.hist, hu.sortb);

  // sort 512 (pad with zeros); rank r lands at sortb[r]. Scnt >= 100 always
  // (8000 keys exist), so ranks 0..99 are real candidates.
  for (int i = Scnt + tid; i < kSortN; i += 256) hu.sortb[i] = 0;
  __syncthreads();
  bitonic512_desc(hu.sortb);

  if (tid < kMaxDet) {
    uint64_t myk = hu.sortb[tid];
    float sv = __uint_as_float((uint32_t)(myk >> 16));
    int f = 0xFFFF - (int)(myk & 0xFFFF);
    int cls = f / 100;
    const float* bp = cls_boxes + ((size_t)b * M + f) * 4;
    float m = (sv > 0.0f) ? 1.0f : 0.0f; // fin_b zeroed where fin_s <= 0
    float* ob = out + ((size_t)b * kMaxDet + tid) * 4;
    ob[0] = bp[0] * m; ob[1] = bp[1] * m; ob[2] = bp[2] * m; ob[3] = bp[3] * m;
    out[(size_t)kB * kMaxDet * 4 + (size_t)b * kMaxDet + tid] = (float)cls;
    out[(size_t)kB * kMaxDet * 5 + (size_t)b * kMaxDet + tid] = sv;
  }
}

extern "C" void kernel_launch(void* const* d_in, const int* in_sizes, int n_in,
                              void* d_out, int out_size, void* d_ws, size_t ws_size,
                              hipStream_t stream) {
  (void)in_sizes; (void)n_in; (void)out_size;
  const float* regs = (const float*)d_in[0];
  const float* ctrs = (const float*)d_in[1];
  const float* clfs = (const float*)d_in[2];
  float* out = (float*)d_out;

  const size_t glB  = (size_t)kRows * kCap * sizeof(uint64_t);      // 15.7 MB
  const size_t cbB  = (size_t)kRows * kMaxPC * 4 * sizeof(float);   // 2.0 MB
  const size_t csB  = (size_t)kRows * kMaxPC * sizeof(float);       // 0.5 MB
  const size_t cntB = 8192;                                          // 1280 u32, padded
  if (ws_size < glB + cbB + csB + cntB) return;  // fail visibly, no OOB

  char* p = (char*)d_ws;
  uint64_t* glist   = (uint64_t*)p; p += glB;
  float* cls_boxes  = (float*)p;    p += cbB;
  float* cls_scores = (float*)p;    p += csB;
  uint32_t* gcnt    = (uint32_t*)p;

  // memset node instead of a zeroing kernel: one fewer dispatch in the graph
  hipMemsetAsync(gcnt, 0, (size_t)kRows * sizeof(uint32_t), stream);
  score_scan_kernel<<<dim3(kGScan, kB), 256, 0, stream>>>(clfs, ctrs, gcnt, glist);
  nms_class_kernel<<<kRows, 256, 0, stream>>>(gcnt, glist, clfs, ctrs, regs,
                                              cls_boxes, cls_scores);
  final_topk_kernel<<<kB, 256, 0, stream>>>(cls_scores, cls_boxes, out);
}

// Round 5
// 242.894 us; speedup vs baseline: 1.1135x; 1.1135x over previous
//
#include <hip/hip_runtime.h>
#include <stdint.h>

// Keep every f32 op un-fused: the reference (numpy/jax f32) computes
// inter = ih*iw; union = a_i + a_j - inter as separate rounded ops. With
// HIP's default -ffp-contract=fast the subtract would fuse into an FMA and
// could flip borderline iou > 0.5 decisions -> wrong box selected.
#pragma clang fp contract(off)

namespace {
constexpr int kN = 21824;      // 128^2 + 64^2 + 32^2 + 16^2 + 8^2
constexpr int kB = 16;
constexpr int kC = 80;
constexpr int kK = 256;        // K_CAND
constexpr int kMaxPC = 100;
constexpr int kMaxDet = 100;
constexpr int kBins1 = 2048;   // level-0 histogram bins
constexpr int kCap = 1536;     // per-row global candidate capacity (u64 keys)
constexpr int kSortN = 512;    // qualifier cap == bitonic sort size
constexpr int kRows = kB * kC; // 1280
constexpr int kTiles = kN / 64;            // 341
constexpr int kTPB = 6;                    // tiles (of 64 anchors) per scan block
constexpr int kGScan = (kTiles + kTPB - 1) / kTPB;   // 57 blocks per batch
constexpr int kLCap = 48;      // per-class per-block LDS list capacity
// Prune floor for the fast path. For this benchmark's product-of-uniforms
// scores, #(s > 0.72) per row ~ mean 950, sd 30 -> inside [kK, kCap] with
// ~10-sigma margin; per-block per-class count ~ mean 17, sd 4 -> < kLCap
// with ~7.8-sigma margin. ANY violation routes to the exact fallback
// (overflow marks the row counter > kCap), so this is a speed heuristic
// only, never a correctness assumption.
constexpr float kThr = 0.72f;
// phase A task count: word w (of 8) serves rows 0..32(w+1)-1.
constexpr int kTasks = 1152;   // sum_{w=0}^{7} 32(w+1)
}

// ---- 48-bit sort key: score bits (high 32) | (0xFFFF - index) (low 16) ----
// scores are >= 0 so the raw f32 bit pattern is order-monotone; the index
// complement reproduces jax top_k's stable tie-break (lower index wins).
__device__ __forceinline__ uint64_t make_key(float s, int n) {
  return ((uint64_t)__float_as_uint(s) << 16) | (uint32_t)(0xFFFF - n);
}

// Block-wide (256 threads) inclusive prefix scan.
__device__ uint32_t block_scan_incl(uint32_t val) {
  __shared__ uint32_t wsum[4];
  int lane = threadIdx.x & 63;
  int wave = threadIdx.x >> 6;
  for (int d = 1; d < 64; d <<= 1) {
    uint32_t t = __shfl_up(val, (unsigned)d, 64);
    if (lane >= d) val += t;
  }
  if (lane == 63) wsum[wave] = val;
  __syncthreads();
  uint32_t off = 0;
  for (int w = 0; w < wave; ++w) off += wsum[w];
  __syncthreads();
  return val + off;
}

// ---- key sources for the refinement select ----
// each(f): f(key) for valid keys only (may be lane-divergent; used for
//          histogram passes where atomics are address-spread).
// each2(f): f(key, valid) executed CONVERGENTLY by every lane of every wave
//          (fixed trip count) -> safe for __ballot aggregation in f.
// Fast path: <=6 list keys per thread, held in registers.
struct RegSrc {
  uint64_t k[6];
  int cnt;                      // valid entries in k[] (prefix)
  template <class F> __device__ void each(F f) const {
    #pragma unroll
    for (int j = 0; j < 6; ++j)
      if (j < cnt) f(k[j]);
  }
  template <class F> __device__ void each2(F f) const {
    #pragma unroll
    for (int j = 0; j < 6; ++j) f(k[j], j < cnt);   // k[j] garbage if !valid; q anded with valid
  }
};
// Exact fallback: recompute scores from the strided class column each pass.
struct ColSrc {
  const float* cl;              // clfs + b*kN*kC + c  (stride kC)
  const float* ct;              // ctrs + b*kN
  template <class F> __device__ void each(F f) const {
    for (int n = threadIdx.x; n < kN; n += 256)
      f(make_key(cl[(size_t)n * kC] * ct[n], n));
  }
  template <class F> __device__ void each2(F f) const {
    constexpr int kNr = (kN + 255) & ~255;
    for (int n = threadIdx.x; n < kNr; n += 256) {
      bool v = n < kN;
      float s = v ? cl[(size_t)n * kC] * ct[n] : 0.0f;
      f(make_key(s, n), v);
    }
  }
};
struct ArrSrc {
  const float* s;
  int count;
  template <class F> __device__ void each(F f) const {
    for (int i = threadIdx.x; i < count; i += 256) f(make_key(s[i], i));
  }
  template <class F> __device__ void each2(F f) const {
    int cr = (count + 255) & ~255;
    for (int i = threadIdx.x; i < cr; i += 256) {
      bool v = i < count;
      float sv = v ? s[i] : 0.0f;
      f(make_key(sv, i), v);
    }
  }
};

// ---- exact top-K floor via histogram refinement, then gather qualifiers.
// Generic (FAST=false): level-0 bins = top 11 key bits (k >> 37).
// FAST=true (nms fast path): every key's score is in (kThr, 1.0) -> float
// exponent is exactly 126 -> key bits [47:39] are the constant 0x7E. Binning
// on the next-lower mantissa bits, bin = (k >> 28) & 0x7FF, is then
// order-monotone (all higher bits equal) and spreads the ~950 keys over
// ~1100 bins (vs 3 hot bins for the generic binning). The refinement loop
// below still handles Sge > cap for either binning (prefix carries the
// constant top bits), so this is a speed specialization only.
// The final gather is wave-aggregated: __ballot + one atomic per wave per
// key slot, instead of ~950 serialized same-address atomicAdd returns.
// Returns Scnt (= #keys >= floor, K <= Scnt <= cap) with the qualifiers in
// cbuf[0..Scnt) (unordered -- the caller sorts).
template <class Src, bool FAST>
__device__ int refine_gather(const Src& src, int K, int cap,
                             uint32_t* hist, uint64_t* cbuf) {
  __shared__ int sel_bin;
  __shared__ uint32_t sel_hd, sel_above, qcnt;
  int tid = threadIdx.x;

  for (int i = tid; i < kBins1; i += 256) hist[i] = 0;
  __syncthreads();
  src.each([&](uint64_t k) {
    uint32_t bin = FAST ? (uint32_t)((k >> 28) & 0x7FF) : (uint32_t)(k >> 37);
    atomicAdd(&hist[bin], 1u);
  });
  __syncthreads();
  uint32_t krem = (uint32_t)K;
  {
    uint32_t bl[8], v = 0;
    int base = kBins1 - 1 - 8 * tid;      // descending scan, 8 bins/thread
    for (int j = 0; j < 8; ++j) { bl[j] = hist[base - j]; v += bl[j]; }
    uint32_t S = block_scan_incl(v);
    if (S >= krem && (S - v) < krem) {
      uint32_t cum = S - v;
      for (int j = 0; j < 8; ++j) {
        cum += bl[j];
        if (cum >= krem) { sel_bin = base - j; sel_hd = bl[j]; sel_above = cum - bl[j]; break; }
      }
    }
    __syncthreads();
  }
  // prefix = all key bits above `shift`; for FAST include the constant
  // exponent bits: (k>>28) = (0x7E << 11) | bin = 0x3F000 | bin.
  uint64_t prefix = FAST ? (uint64_t)(0x3F000u | (uint32_t)sel_bin)
                         : (uint64_t)sel_bin;
  int shift = FAST ? 28 : 37;
  krem = (uint32_t)K - sel_above;
  uint32_t Sge = ((uint32_t)K - krem) + sel_hd;
  __syncthreads();

  while (Sge > (uint32_t)cap) {
    int w = (shift > 8) ? 8 : shift;
    int ns = shift - w, bins = 1 << w, hs = shift;
    for (int i = tid; i < bins; i += 256) hist[i] = 0;
    __syncthreads();
    uint64_t pfx = prefix;
    src.each([&](uint64_t k) {
      if ((k >> hs) == pfx)
        atomicAdd(&hist[(uint32_t)(k >> ns) & (bins - 1)], 1u);
    });
    __syncthreads();
    uint32_t v = (tid < bins) ? hist[bins - 1 - tid] : 0;
    uint32_t S = block_scan_incl(v);
    if (v && S >= krem && (S - v) < krem) {
      sel_bin = bins - 1 - tid; sel_hd = v; sel_above = S - v;
    }
    __syncthreads();
    prefix = (prefix << w) | (uint32_t)sel_bin;
    krem -= sel_above;
    Sge = ((uint32_t)K - krem) + sel_hd;
    shift = ns;
    __syncthreads();
  }

  uint64_t L = prefix << shift;
  if (tid == 0) qcnt = 0;
  __syncthreads();
  {
    int lane = tid & 63;
    uint64_t lmask = (1ull << lane) - 1ull;
    src.each2([&](uint64_t k, bool valid) {
      bool q = valid && (k >= L);
      unsigned long long m = __ballot(q);
      uint32_t base = 0;
      if (lane == 0 && m) base = atomicAdd(&qcnt, (uint32_t)__popcll(m));
      base = __shfl(base, 0, 64);
      if (q) {
        uint32_t p = base + (uint32_t)__popcll(m & lmask);
        if (p < (uint32_t)cap) cbuf[p] = k;
      }
    });
  }
  __syncthreads();
  int Scnt = (int)qcnt;
  return Scnt > cap ? cap : Scnt;       // == Sge <= cap by construction
}

// ---- bitonic sort of 512 keys in LDS, descending, 2 elements/thread. ----
// Thread L owns elements 2L, 2L+1. For element-distance j <= 64 the partner
// lane is L ^ (j/2) -> wave-local __shfl_xor, no LDS, no barrier. Only
// j in {256,128} cross waves (3 phases) and go through LDS. Keys must be
// unique (index bits guarantee it); zero-padding sorts last. Ends with the
// sorted array redistributed to sortb[] (rank r at sortb[r]) + barrier.
__device__ __forceinline__ void bitonic512_desc(uint64_t* sortb) {
  int tid = threadIdx.x;
  uint64_t e0 = sortb[2 * tid], e1 = sortb[2 * tid + 1];
  #pragma unroll
  for (int k2 = 2; k2 <= kSortN; k2 <<= 1) {
    #pragma unroll
    for (int j = k2 >> 1; j >= 2; j >>= 1) {
      bool up = ((tid & (k2 >> 1)) == 0);      // element (2L)&k2 == 0
      uint64_t p0, p1;
      bool low;
      if (j >= 128) {                          // cross-wave via LDS
        __syncthreads();                       // prior reads done
        sortb[2 * tid] = e0; sortb[2 * tid + 1] = e1;
        __syncthreads();
        int pi = (2 * tid) ^ j;                // j even -> partner pair contiguous
        p0 = sortb[pi]; p1 = sortb[pi + 1];
        low = ((tid & (j >> 1)) == 0);
      } else {                                 // wave-local via shuffle
        int d = j >> 1;
        p0 = (uint64_t)__shfl_xor((unsigned long long)e0, d, 64);
        p1 = (uint64_t)__shfl_xor((unsigned long long)e1, d, 64);
        low = ((tid & d) == 0);
      }
      bool keepMax = (up == low);
      e0 = (keepMax == (e0 > p0)) ? e0 : p0;
      e1 = (keepMax == (e1 > p1)) ? e1 : p1;
    }
    { // j == 1: in-thread pair (2L, 2L+1)
      bool up = ((tid & (k2 >> 1)) == 0);
      bool sw = up ? (e0 < e1) : (e0 > e1);
      uint64_t t0 = sw ? e1 : e0, t1 = sw ? e0 : e1;
      e0 = t0; e1 = t1;
    }
  }
  __syncthreads();
  sortb[2 * tid] = e0; sortb[2 * tid + 1] = e1;
  __syncthreads();
}

// ---- fused score (clf*ctr) + prune, two-level append ----
__global__ __launch_bounds__(256) void score_scan_kernel(
    const float* __restrict__ clfs, const float* __restrict__ ctrs,
    uint32_t* __restrict__ gcnt, uint64_t* __restrict__ glist) {
  int b = blockIdx.y;
  int t0 = blockIdx.x * kTPB;
  int t1 = t0 + kTPB; if (t1 > kTiles) t1 = kTiles;
  int nbase = t0 * 64;
  int nanch = (t1 - t0) * 64;

  __shared__ uint64_t lbuf[kC][kLCap + 1]; // +1 pad: append banks spread
  __shared__ uint32_t lcnt[kC];
  __shared__ uint32_t gbase[kC];
  __shared__ float ct[kTPB * 64];
  int tid = threadIdx.x;
  for (int i = tid; i < kC; i += 256) lcnt[i] = 0;
  for (int i = tid; i < nanch; i += 256) ct[i] = ctrs[(size_t)b * kN + nbase + i];
  __syncthreads();

  const float4* src = (const float4*)(clfs + ((size_t)b * kN + nbase) * kC);
  int n4 = nanch * (kC / 4);             // 20 float4 per anchor
  // software prefetch: issue the next global load before the atomic-laden
  // append body (side effects otherwise pin the loads behind the branches).
  float4 v = (tid < n4) ? src[tid] : float4{0, 0, 0, 0};
  for (int e = tid; e < n4; e += 256) {
    int en = e + 256;
    float4 vn = (en < n4) ? src[en] : float4{0, 0, 0, 0};
    int a = e / 20;                      // anchor within chunk
    int c0 = (e % 20) * 4;               // class of component .x (4 | 80)
    float cv = ct[a];
    int n = nbase + a;
    float sv[4] = {v.x * cv, v.y * cv, v.z * cv, v.w * cv};
    #pragma unroll
    for (int j = 0; j < 4; ++j) {
      if (sv[j] > kThr) {
        int c = c0 + j;
        uint32_t p = atomicAdd(&lcnt[c], 1u);
        if (p < kLCap) lbuf[c][p] = make_key(sv[j], n);
      }
    }
    v = vn;
  }
  __syncthreads();

  // parallel reservations: 80 concurrent global atomics (lanes), then copy.
  if (tid < kC) {
    uint32_t m = lcnt[tid];
    int row = b * kC + tid;
    if (m > kLCap) {                     // overflow -> force exact fallback
      atomicAdd(&gcnt[row], (uint32_t)(kCap + 1));
      gbase[tid] = 0xFFFFFFFFu;
    } else {
      gbase[tid] = m ? atomicAdd(&gcnt[row], m) : 0u;
    }
  }
  __syncthreads();

  int lane = tid & 63, wave = tid >> 6;
  for (int c = wave * 20; c < wave * 20 + 20; ++c) {
    uint32_t m = lcnt[c];
    uint32_t base = gbase[c];
    if (base == 0xFFFFFFFFu || m == 0) continue;
    if (m > kLCap) m = kLCap;
    int row = b * kC + c;
    for (uint32_t i = lane; i < m; i += 64) {
      uint32_t p = base + i;
      if (p < kCap) glist[(size_t)row * kCap + p] = lbuf[c][i];
    }
  }
}

// ---- per-(batch,class): list -> exact top-256 -> bit-matrix NMS -> top-100 ----
__global__ __launch_bounds__(256) void nms_class_kernel(
    const uint32_t* __restrict__ gcnt, const uint64_t* __restrict__ glist,
    const float* __restrict__ clfs, const float* __restrict__ ctrs,
    const float* __restrict__ regs,
    float* __restrict__ cls_boxes, float* __restrict__ cls_scores) {
  int row = blockIdx.x;
  int b = row / kC, c = row % kC;
  int tid = threadIdx.x;
  int lane = tid & 63, wave = tid >> 6;

  __shared__ union alignas(16) {
    uint32_t hist[kBins1];               // select phase (8 KB)
    uint64_t sortb[kSortN];              // qualifier + sort buffer (4 KB)
    uint32_t supm[kK][8];                // NMS suppression bit-matrix (8 KB)
  } hu;
  __shared__ float4 boxf4[kK];           // y1,x1,y2,x2 (4 KB)
  __shared__ float barea[kK];
  __shared__ uint32_t rnz[8];            // bit r of word w: sup row 32w+r != 0
  __shared__ uint64_t kinit[4];          // initial keep mask (valid bits)
  __shared__ uint64_t kfin[4];           // final keep mask

  // fast path: pruned list holds a superset of the top-256
  // (cnt >= kK  ==> the 256th-largest score > kThr ==> all top-256 listed;
  //  cnt <= kCap ==> no block overflowed and no append was dropped)
  uint32_t cnt = gcnt[row];
  int Scnt;
  if (cnt >= (uint32_t)kK && cnt <= (uint32_t)kCap) {
    RegSrc rs; rs.cnt = 0;
    const uint64_t* gl = glist + (size_t)row * kCap;
    #pragma unroll
    for (int j = 0; j < 6; ++j) {
      int i = tid + j * 256;
      if (i < (int)cnt) { rs.k[j] = gl[i]; rs.cnt = j + 1; }
    }
    // gather straight into the sort buffer (hist region is dead by then);
    // FAST binning: all keys have score in (kThr,1) -> exp bits constant.
    Scnt = refine_gather<RegSrc, true>(rs, kK, kSortN, hu.hist, hu.sortb);
  } else {
    ColSrc cs{clfs + (size_t)b * kN * kC + c, ctrs + (size_t)b * kN};
    Scnt = refine_gather<ColSrc, false>(cs, kK, kSortN, hu.hist, hu.sortb);
  }

  // sort 512 (pad with zeros), rank tid == thread tid's candidate
  for (int i = Scnt + tid; i < kSortN; i += 256) hu.sortb[i] = 0;
  __syncthreads();
  bitonic512_desc(hu.sortb);
  uint64_t myk = hu.sortb[tid];
  __syncthreads();                       // all sortb reads before supm zero

  // decode my candidate's box directly from regs (fused decode)
  int n = 0xFFFF - (int)(myk & 0xFFFF);
  float sc_v = __uint_as_float((uint32_t)(myk >> 16));
  int off, hl;
  float sf;
  if (n < 16384)      { off = 0;     hl = 7; sf = 8.f;   }
  else if (n < 20480) { off = 16384; hl = 6; sf = 16.f;  }
  else if (n < 21504) { off = 20480; hl = 5; sf = 32.f;  }
  else if (n < 21760) { off = 21504; hl = 4; sf = 64.f;  }
  else                { off = 21760; hl = 3; sf = 128.f; }
  int kk = n - off;
  // meshgrid(h, w) with 'xy' indexing -> gy = k % H, gx = k / H
  float gx = (float)(kk >> hl);
  float gy = (float)(kk & ((1 << hl) - 1));
  const float4 r = ((const float4*)regs)[(size_t)b * kN + n];
  float4 mybox;
  mybox.x = (gy - r.z) * sf;             // y1
  mybox.y = (gx - r.x) * sf;             // x1
  mybox.z = (gy + r.w) * sf;             // y2
  mybox.w = (gx + r.y) * sf;             // x2
  float my_a = (mybox.z - mybox.x) * (mybox.w - mybox.y);
  boxf4[tid] = mybox;
  barea[tid] = my_a;
  unsigned long long vm = __ballot(sc_v > 0.05f);   // valid = top_s > CONF_THR
  if (lane == 0) kinit[wave] = vm;
  // zero the suppression matrix + nz bitmap (sortb/hist no longer needed)
  {
    uint64_t* sp = (uint64_t*)&hu.supm[0][0];
    #pragma unroll
    for (int q = 0; q < 4; ++q) sp[tid + q * 256] = 0;
    if (tid < 8) rnz[tid] = 0;
  }
  __syncthreads();

  // phase A: balanced (row,word) task decomposition. Word w of the 8
  // suppression words is needed by rows 0..32(w+1)-1 (word w >= row/32),
  // giving kTasks=1152 tasks; dealt round-robin every thread gets 4-5 (vs
  // 8-words-for-wave-0 under row-owner split -> critical wave halves).
  // A wave's 64 consecutive task ids share the same word except at the 7
  // group boundaries (<=2 distinct words -> 2-way broadcast, free), so the
  // B-column reads stay conflict-free; A-row reads are consecutive-lane.
  // Each task is the unique writer of supm[r][w] -> plain store, no atomic.
  // Exact predicate: RN(inter/unc) > 0.5  <=>  inter > (0.5+2^-25)*unc
  // (tie rounds-to-even down)  <=>  inter+inter > unc in pure f32 (no f32
  // value lies in (unc/2, (0.5+2^-25)*unc] since ulp(u)/u > 2^-24 for
  // normals; unc >= 1e-8 is always normal). Bit-exact vs the reference.
  for (int t = tid; t < kTasks; t += 256) {
    // start(w) = 16w(w+1): 0,32,96,192,320,480,672,896
    int w = (t >= 32) + (t >= 96) + (t >= 192) + (t >= 320) +
            (t >= 480) + (t >= 672) + (t >= 896);
    int rr = t - 16 * w * (w + 1);
    float4 A = boxf4[rr];
    float aA = barea[rr];
    const float4* bp = boxf4 + (w << 5);
    const float* ap = barea + (w << 5);
    uint32_t cur = 0;
    #pragma unroll
    for (int s = 0; s < 32; ++s) {
      const float4 Bx = bp[s];
      float aB = ap[s];
      float yy1 = fmaxf(A.x, Bx.x);
      float yy2 = fminf(A.z, Bx.z);
      float xx1 = fmaxf(A.y, Bx.y);
      float xx2 = fminf(A.w, Bx.w);
      float ih = fmaxf(yy2 - yy1, 0.0f);
      float iw = fmaxf(xx2 - xx1, 0.0f);
      float inter = ih * iw;
      float un = (aB + aA) - inter;
      float unc = fmaxf(un, 1e-8f);
      cur |= (inter + inter > unc) ? (1u << s) : 0u;
    }
    // diagonal word keeps only cols j > rr; full words keep all (j >= 32w > rr)
    uint32_t mask = (w == (rr >> 5)) ? (0xFFFFFFFEu << (rr & 31)) : 0xFFFFFFFFu;
    cur &= mask;
    hu.supm[rr][w] = cur;
    if (cur) atomicOr(&rnz[rr >> 5], 1u << (rr & 31));
  }
  __syncthreads();

  // phase B: greedy resolution by wave 0 only. Sparse skip: a row with an
  // all-zero sup row is a no-op in the greedy chain regardless of its keep
  // bit (kw &= ~0), so only chunks containing a nonzero row (per rnz) are
  // loaded+applied -- for this data's sparse overlaps that's a handful of
  // the 64 chunks. Rows are loaded as 2x ds_read_b128 (32B-aligned).
  if (wave == 0) {
    uint64_t kw0 = kinit[0], kw1 = kinit[1], kw2 = kinit[2], kw3 = kinit[3];
    uint64_t wn0 = rnz[0] | ((uint64_t)rnz[1] << 32);
    uint64_t wn1 = rnz[2] | ((uint64_t)rnz[3] << 32);
    uint64_t wn2 = rnz[4] | ((uint64_t)rnz[5] << 32);
    uint64_t wn3 = rnz[6] | ((uint64_t)rnz[7] << 32);
    #define NMS_SECTION(W, KW, WN)                                          \
      _Pragma("unroll")                                                     \
      for (int ch = 0; ch < 16; ++ch) {                                     \
        if ((WN >> (ch * 4)) & 0xFull) {                                    \
          const ulonglong2* s0 = (const ulonglong2*)hu.supm[(W << 6) + ch * 4 + 0]; \
          const ulonglong2* s1 = (const ulonglong2*)hu.supm[(W << 6) + ch * 4 + 1]; \
          const ulonglong2* s2 = (const ulonglong2*)hu.supm[(W << 6) + ch * 4 + 2]; \
          const ulonglong2* s3 = (const ulonglong2*)hu.supm[(W << 6) + ch * 4 + 3]; \
          ulonglong2 aL = s0[0], aH = s0[1];                                \
          ulonglong2 bL = s1[0], bH = s1[1];                                \
          ulonglong2 cL = s2[0], cH = s2[1];                                \
          ulonglong2 dL = s3[0], dH = s3[1];                                \
          if ((KW >> (ch * 4 + 0)) & 1ull) { kw0 &= ~aL.x; kw1 &= ~aL.y; kw2 &= ~aH.x; kw3 &= ~aH.y; } \
          if ((KW >> (ch * 4 + 1)) & 1ull) { kw0 &= ~bL.x; kw1 &= ~bL.y; kw2 &= ~bH.x; kw3 &= ~bH.y; } \
          if ((KW >> (ch * 4 + 2)) & 1ull) { kw0 &= ~cL.x; kw1 &= ~cL.y; kw2 &= ~cH.x; kw3 &= ~cH.y; } \
          if ((KW >> (ch * 4 + 3)) & 1ull) { kw0 &= ~dL.x; kw1 &= ~dL.y; kw2 &= ~dH.x; kw3 &= ~dH.y; } \
        }                                                                   \
      }
    NMS_SECTION(0, kw0, wn0)
    NMS_SECTION(1, kw1, wn1)
    NMS_SECTION(2, kw2, wn2)
    NMS_SECTION(3, kw3, wn3)
    #undef NMS_SECTION
    if (lane == 0) { kfin[0] = kw0; kfin[1] = kw1; kfin[2] = kw2; kfin[3] = kw3; }
  }
  __syncthreads();

  uint64_t kw0 = kfin[0], kw1 = kfin[1], kw2 = kfin[2], kw3 = kfin[3];
  uint64_t ww = (wave == 0) ? kw0 : (wave == 1) ? kw1 : (wave == 2) ? kw2 : kw3;
  bool keptf = (ww >> lane) & 1ull;
  int kept_total = (int)(__popcll(kw0) + __popcll(kw1) +
                         __popcll(kw2) + __popcll(kw3));
  int kept_before = (int)__popcll(ww & ((1ull << lane) - 1ull));
  if (wave > 0) kept_before += (int)__popcll(kw0);
  if (wave > 1) kept_before += (int)__popcll(kw1);
  if (wave > 2) kept_before += (int)__popcll(kw2);

  // stable top-100 of kept scores: kept candidates are already in descending
  // (score,-index) order; zero slots tie-break by position. Final order =
  // kept (tid order) then suppressed (tid order) == reference stable top_k.
  int rank2 = keptf ? kept_before : (kept_total + tid - kept_before);
  if (rank2 < kMaxPC) {
    float ks = keptf ? sc_v : 0.0f;
    size_t obase = ((size_t)row) * kMaxPC + rank2;
    cls_scores[obase] = ks;
    float* ob = cls_boxes + obase * 4;
    ob[0] = mybox.x; ob[1] = mybox.y; ob[2] = mybox.z; ob[3] = mybox.w;
  }
}

// ---- per-batch: stable top-100 over 80*100 entries, write final outputs ----
__global__ __launch_bounds__(256) void final_topk_kernel(
    const float* __restrict__ cls_scores, const float* __restrict__ cls_boxes,
    float* __restrict__ out) {
  int b = blockIdx.x;
  int tid = threadIdx.x;
  const int M = kC * kMaxPC;  // 8000
  __shared__ union alignas(16) {
    uint32_t hist[kBins1];               // 8 KB
    uint64_t sortb[kSortN];              // 4 KB (hist dead at gather time)
  } hu;

  ArrSrc as{cls_scores + (size_t)b * M, M};
  int Scnt = refine_gather<ArrSrc, false>(as, kMaxDet, kSortN, hu.hist, hu.sortb);

  // sort 512 (pad with zeros); rank r lands at sortb[r]. Scnt >= 100 always
  // (8000 keys exist), so ranks 0..99 are real candidates.
  for (int i = Scnt + tid; i < kSortN; i += 256) hu.sortb[i] = 0;
  __syncthreads();
  bitonic512_desc(hu.sortb);

  if (tid < kMaxDet) {
    uint64_t myk = hu.sortb[tid];
    float sv = __uint_as_float((uint32_t)(myk >> 16));
    int f = 0xFFFF - (int)(myk & 0xFFFF);
    int cls = f / 100;
    const float* bp = cls_boxes + ((size_t)b * M + f) * 4;
    float m = (sv > 0.0f) ? 1.0f : 0.0f; // fin_b zeroed where fin_s <= 0
    float* ob = out + ((size_t)b * kMaxDet + tid) * 4;
    ob[0] = bp[0] * m; ob[1] = bp[1] * m; ob[2] = bp[2] * m; ob[3] = bp[3] * m;
    out[(size_t)kB * kMaxDet * 4 + (size_t)b * kMaxDet + tid] = (float)cls;
    out[(size_t)kB * kMaxDet * 5 + (size_t)b * kMaxDet + tid] = sv;
  }
}

extern "C" void kernel_launch(void* const* d_in, const int* in_sizes, int n_in,
                              void* d_out, int out_size, void* d_ws, size_t ws_size,
                              hipStream_t stream) {
  (void)in_sizes; (void)n_in; (void)out_size;
  const float* regs = (const float*)d_in[0];
  const float* ctrs = (const float*)d_in[1];
  const float* clfs = (const float*)d_in[2];
  float* out = (float*)d_out;

  const size_t glB  = (size_t)kRows * kCap * sizeof(uint64_t);      // 15.7 MB
  const size_t cbB  = (size_t)kRows * kMaxPC * 4 * sizeof(float);   // 2.0 MB
  const size_t csB  = (size_t)kRows * kMaxPC * sizeof(float);       // 0.5 MB
  const size_t cntB = 8192;                                          // 1280 u32, padded
  if (ws_size < glB + cbB + csB + cntB) return;  // fail visibly, no OOB

  char* p = (char*)d_ws;
  uint64_t* glist   = (uint64_t*)p; p += glB;
  float* cls_boxes  = (float*)p;    p += cbB;
  float* cls_scores = (float*)p;    p += csB;
  uint32_t* gcnt    = (uint32_t*)p;

  // memset node instead of a zeroing kernel: one fewer dispatch in the graph
  hipMemsetAsync(gcnt, 0, (size_t)kRows * sizeof(uint32_t), stream);
  score_scan_kernel<<<dim3(kGScan, kB), 256, 0, stream>>>(clfs, ctrs, gcnt, glist);
  nms_class_kernel<<<kRows, 256, 0, stream>>>(gcnt, glist, clfs, ctrs, regs,
                                              cls_boxes, cls_scores);
  final_topk_kernel<<<kB, 256, 0, stream>>>(cls_scores, cls_boxes, out);
}